// Round 11
// baseline (416.492 us; speedup 1.0000x reference)
//
#include <hip/hip_runtime.h>
#include <hip/hip_bf16.h>
#include <stdint.h>

#define L_ 25
#define E_ 64
#define H_ 8
#define B_ 1000
#define S_ 512
#define GQ 4                       // batch elements per block
#define NCELL (L_ * GQ)            // 100 cells per block
#define TPBR (NCELL * 8)           // 800 threads, thread = (cell, j)
#define TS 4                       // timesteps per superstep
#define NSUPER (S_ / TS + L_ - 1)  // 152 supersteps
#define XG 36                      // per-cell stride xbuf: 144B (16B-aligned)

typedef float v2f __attribute__((ext_vector_type(2)));
typedef float v4f __attribute__((ext_vector_type(4)));

#define PIN(x) asm volatile("" : "+v"(x))

// v_pk_fma_f32: {a.x*b.x+c.x, a.y*b.y+c.y}
__device__ __forceinline__ v2f pkfma(v2f a, v2f b, v2f c) {
  v2f d;
  asm("v_pk_fma_f32 %0, %1, %2, %3" : "=v"(d) : "v"(a), "v"(b), "v"(c));
  return d;
}
// op_sel broadcast of a.x: {a.x*b.x+c.x, a.x*b.y+c.y}
__device__ __forceinline__ v2f pkfma_l(v2f a, v2f b, v2f c) {
  v2f d;
  asm("v_pk_fma_f32 %0, %1, %2, %3 op_sel:[0,0,0] op_sel_hi:[0,1,1]"
      : "=v"(d) : "v"(a), "v"(b), "v"(c));
  return d;
}
// op_sel broadcast of a.y: {a.y*b.x+c.x, a.y*b.y+c.y}
__device__ __forceinline__ v2f pkfma_h(v2f a, v2f b, v2f c) {
  v2f d;
  asm("v_pk_fma_f32 %0, %1, %2, %3 op_sel:[1,0,0] op_sel_hi:[1,1,1]"
      : "=v"(d) : "v"(a), "v"(b), "v"(c));
  return d;
}
__device__ __forceinline__ v2f pkadd(v2f a, v2f b) {
  v2f d;
  asm("v_pk_add_f32 %0, %1, %2" : "=v"(d) : "v"(a), "v"(b));
  return d;
}
__device__ __forceinline__ v2f vlo(v4f v) { return __builtin_shufflevector(v, v, 0, 1); }
__device__ __forceinline__ v2f vhi(v4f v) { return __builtin_shufflevector(v, v, 2, 3); }
__device__ __forceinline__ v2f mk2(float a, float b) { v2f r; r.x = a; r.y = b; return r; }

// DPP lane permute within 8-lane cell group (no LDS, no barrier, no repack):
// 0xB1 = quad_perm[1,0,3,2] (j^1), 0x4E = quad_perm[2,3,0,1] (j^2),
// 0x141 = row_half_mirror (j^7 within 8-lane half-row)
template <int CTRL>
__device__ __forceinline__ float dppf(float v) {
  return __int_as_float(
      __builtin_amdgcn_mov_dpp(__float_as_int(v), CTRL, 0xF, 0xF, false));
}

// full zr chain over 8 k's (off-critical-path x side)
#define CHAIN8(acc, ma, mb, w)            \
  acc = pkfma_l(vlo(ma), w[0], acc);      \
  acc = pkfma_h(vlo(ma), w[1], acc);      \
  acc = pkfma_l(vhi(ma), w[2], acc);      \
  acc = pkfma_h(vhi(ma), w[3], acc);      \
  acc = pkfma_l(vlo(mb), w[4], acc);      \
  acc = pkfma_h(vlo(mb), w[5], acc);      \
  acc = pkfma_l(vhi(mb), w[6], acc);      \
  acc = pkfma_h(vhi(mb), w[7], acc);

// half zr chain over 4 k's of one v4f (critical-path h side, 2-way split)
#define CHAIN4L(acc, ma, w0, w1, w2, w3)  \
  acc = pkfma_l(vlo(ma), w0, acc);        \
  acc = pkfma_h(vlo(ma), w1, acc);        \
  acc = pkfma_l(vhi(ma), w2, acc);        \
  acc = pkfma_h(vhi(ma), w3, acc);

// element-wise paired chain (x side)
#define CHAIN4P(acc, ma, mb, w)           \
  acc = pkfma(vlo(ma), w[0], acc);        \
  acc = pkfma(vhi(ma), w[1], acc);        \
  acc = pkfma(vlo(mb), w[2], acc);        \
  acc = pkfma(vhi(mb), w[3], acc);

__device__ __forceinline__ float ulo(uint32_t u) { return __uint_as_float(u << 16); }
__device__ __forceinline__ float uhi(uint32_t u) { return __uint_as_float(u & 0xffff0000u); }

__device__ __forceinline__ float toF(float v) { return v; }
__device__ __forceinline__ float toF(__hip_bfloat16 v) { return __bfloat162float(v); }
__device__ __forceinline__ void stP(float* p, float v) { *p = v; }
__device__ __forceinline__ void stP(__hip_bfloat16* p, float v) { *p = __float2bfloat16(v); }

__device__ __forceinline__ v2f loadC2(const float* p) { return *(const v2f*)p; }
__device__ __forceinline__ v2f loadC2(const __hip_bfloat16* p) {
  const uint32_t u = *(const uint32_t*)p;
  return mk2(ulo(u), uhi(u));
}

__device__ __forceinline__ void load8f(const __hip_bfloat16* p, float* o) {
  const uint4 v = *(const uint4*)p;
  o[0] = ulo(v.x); o[1] = uhi(v.x); o[2] = ulo(v.y); o[3] = uhi(v.y);
  o[4] = ulo(v.z); o[5] = uhi(v.z); o[6] = ulo(v.w); o[7] = uhi(v.w);
}
__device__ __forceinline__ void load8f(const float* p, float* o) {
  const float4 a = ((const float4*)p)[0];
  const float4 b = ((const float4*)p)[1];
  o[0] = a.x; o[1] = a.y; o[2] = a.z; o[3] = a.w;
  o[4] = b.x; o[5] = b.y; o[6] = b.z; o[7] = b.w;
}

__device__ __forceinline__ void st4(float* p, float a, float b, float c, float d) {
  float4 v; v.x = a; v.y = b; v.z = c; v.w = d;
  *(float4*)p = v;
}
__device__ __forceinline__ void st4(__hip_bfloat16* p, float a, float b, float c, float d) {
  __hip_bfloat16 t[4] = {__float2bfloat16(a), __float2bfloat16(b),
                         __float2bfloat16(c), __float2bfloat16(d)};
  *(ushort4*)p = *(ushort4*)t;
}

__device__ __forceinline__ float sigmo(float x) {
  return __builtin_amdgcn_rcpf(1.f + __expf(-x));
}

// Per-block dtype probe: max |bf16| of first 256 shorts of emb.
__device__ __forceinline__ void detect64(const unsigned short* __restrict__ u,
                                         int tid, float* fl) {
  if (tid < 64) {
    float m = 0.f;
#pragma unroll
    for (int k = 0; k < 4; ++k) {
      const uint32_t q = u[tid * 4 + k];
      float v = fabsf(__uint_as_float(q << 16));
      if (!(v < 1e30f)) v = 1e30f;
      m = fmaxf(m, v);
    }
#pragma unroll
    for (int off = 32; off; off >>= 1) m = fmaxf(m, __shfl_down(m, off, 64));
    if (tid == 0) *fl = (m > 2.0f) ? 0.f : 1.f;
  }
}

// ---------------------------------------------------------------------------
// Kernel 1: layer-0 x-projections. pre token layout (24 floats):
// [2j]={z_j}, [2j+1]={r_j}, [16+j]={h_j}.
// ---------------------------------------------------------------------------
template <typename T, typename PT>
__device__ __forceinline__ void pre_body(
    const int* __restrict__ x, const void* __restrict__ embv,
    const void* __restrict__ Wzv, const void* __restrict__ Wrv,
    const void* __restrict__ Whv, PT* __restrict__ pre,
    float* WL, float* TBb) {
  const T* emb = (const T*)embv;
  const T* Wz = (const T*)Wzv;
  const T* Wr = (const T*)Wrv;
  const T* Wh = (const T*)Whv;
  const int tid = threadIdx.x;

  for (int idx = tid; idx < 64 * 24; idx += 256) {
    const int k = idx / 24, c = idx - k * 24;
    float w;
    if (c < 16) w = toF(((c & 1) ? Wr : Wz)[k * 8 + (c >> 1)]);
    else        w = toF(Wh[k * 8 + (c - 16)]);
    WL[idx] = w;
  }
  __syncthreads();

  const int tok = blockIdx.x * 256 + tid;
  const int t = x[tok];

  v2f acc[12];
#pragma unroll
  for (int q = 0; q < 12; ++q) acc[q] = mk2(0.f, 0.f);

  for (int kb = 0; kb < 8; ++kb) {
    float e[8];
    load8f(emb + (size_t)t * E_ + kb * 8, e);
#pragma unroll
    for (int k8 = 0; k8 < 8; ++k8) {
      const v4f* wr = (const v4f*)(WL + (kb * 8 + k8) * 24);
      const v2f ee = mk2(e[k8], e[k8]);
#pragma unroll
      for (int q = 0; q < 6; ++q) {
        const v4f w4 = wr[q];
        acc[2 * q]     = pkfma(ee, vlo(w4), acc[2 * q]);
        acc[2 * q + 1] = pkfma(ee, vhi(w4), acc[2 * q + 1]);
      }
    }
  }

  // in-wave transpose: [24][65] per wave, conflict-free
  const int wid = tid >> 6, lane = tid & 63;
  float* tb = TBb + wid * (24 * 65);
#pragma unroll
  for (int q = 0; q < 12; ++q) {
    tb[(2 * q) * 65 + lane] = acc[q].x;
    tb[(2 * q + 1) * 65 + lane] = acc[q].y;
  }
  asm volatile("s_waitcnt lgkmcnt(0)" ::: "memory");
  __builtin_amdgcn_wave_barrier();

  PT* ob = pre + (size_t)(blockIdx.x * 256 + wid * 64) * 24;
#pragma unroll
  for (int it = 0; it < 6; ++it) {
    const int F0 = it * 256 + lane * 4;
    float o[4];
#pragma unroll
    for (int e2 = 0; e2 < 4; ++e2) {
      const int F = F0 + e2;
      const int tk = F / 24;
      const int c = F - tk * 24;
      o[e2] = tb[c * 65 + tk];
    }
    st4(ob + F0, o[0], o[1], o[2], o[3]);
  }
}

template <typename PT>
__global__ __launch_bounds__(256, 4) void gru_pre(
    const int* __restrict__ x, const void* __restrict__ emb,
    const void* __restrict__ Wz, const void* __restrict__ Wr,
    const void* __restrict__ Wh, PT* __restrict__ pre) {
  __shared__ __align__(16) float WL[64 * 24];
  __shared__ __align__(16) float TB[4][24 * 65];
  __shared__ float fl;
  detect64((const unsigned short*)emb, threadIdx.x, &fl);
  __syncthreads();
  if (fl != 0.f) pre_body<__hip_bfloat16, PT>(x, emb, Wz, Wr, Wh, pre, WL, &TB[0][0]);
  else           pre_body<float, PT>(x, emb, Wz, Wr, Wh, pre, WL, &TB[0][0]);
}

// ---------------------------------------------------------------------------
// One timestep. hr exchange is a DPP butterfly consumed by SCALAR fmafs
// (no LDS round trip, no repack). zr h-chain split 4+4; z-path of the
// update hoisted off the post-gather chain. axh = H-gate x-part (scalar).
// Weight order for the H-gate is the butterfly order j^{0,1,2,3,7,6,5,4}
// (folded into wrhS load). xc write doubles as h propagation.
// ---------------------------------------------------------------------------
#define TSTEP(hprev, axK, axh, h01, h23, slotT, hnout)                 \
  {                                                                    \
    v2f hA_ = bzr;                                                     \
    CHAIN4L(hA_, h01, wzrh[0], wzrh[1], wzrh[2], wzrh[3]);             \
    v2f hB_ = axK;                                                     \
    CHAIN4L(hB_, h23, wzrh[4], wzrh[5], wzrh[6], wzrh[7]);             \
    const v2f azr_ = pkadd(hA_, hB_);                                  \
    const float r_ = sigmo(azr_.y);                                    \
    const float ez_ = __expf(fminf(-azr_.x, 30.f));                    \
    const float ez1_ = 1.f + ez_;                                      \
    const float t_ = (hprev) * ez_;                                    \
    const float tm1_ = t_ - 1.f;                                       \
    const float tp1_ = t_ + 1.f;                                       \
    const float g0_ = (hprev) * r_;                                    \
    const float g1_ = dppf<0xB1>(g0_);                                 \
    const float g2_ = dppf<0x4E>(g0_);                                 \
    const float g3_ = dppf<0x4E>(g1_);                                 \
    const float g7_ = dppf<0x141>(g0_);                                \
    const float g6_ = dppf<0x141>(g1_);                                \
    const float g5_ = dppf<0x141>(g2_);                                \
    const float g4_ = dppf<0x141>(g3_);                                \
    float a0_ = (axh);                                                 \
    a0_ = fmaf(g0_, wrhS[0], a0_);                                     \
    a0_ = fmaf(g1_, wrhS[1], a0_);                                     \
    a0_ = fmaf(g2_, wrhS[2], a0_);                                     \
    a0_ = fmaf(g3_, wrhS[3], a0_);                                     \
    float a1_ = g7_ * wrhS[4];                                         \
    a1_ = fmaf(g6_, wrhS[5], a1_);                                     \
    a1_ = fmaf(g5_, wrhS[6], a1_);                                     \
    a1_ = fmaf(g4_, wrhS[7], a1_);                                     \
    const float ah_ = a0_ + a1_;                                       \
    const float eh_ = __expf(fminf(-2.f * ah_, 30.f));                 \
    const float nu_ = fmaf(eh_, tm1_, tp1_);                           \
    const float de_ = ez1_ * (1.f + eh_);                              \
    hnout = nu_ * __builtin_amdgcn_rcpf(de_);                          \
    xc[(slotT) * 8 + j] = hnout;                                       \
    __builtin_amdgcn_wave_barrier();                                   \
  }

// ---------------------------------------------------------------------------
// Kernel 2: pipelined recurrence, TS=4, GQ=4, global __syncthreads.
// h-exchange in xbuf; hr-exchange via DPP (hrsh LDS buffer deleted).
// ---------------------------------------------------------------------------
template <typename T, typename PT>
__device__ __forceinline__ void rec_body(
    const PT* __restrict__ pre,
    const void* __restrict__ Whz0v, const void* __restrict__ bz0v,
    const void* __restrict__ Whr0v, const void* __restrict__ br0v,
    const void* __restrict__ WrH0v, const void* __restrict__ bH0v,
    const void* __restrict__ Wxzv, const void* __restrict__ Whzv,
    const void* __restrict__ bzv, const void* __restrict__ Wxrv,
    const void* __restrict__ Whrv, const void* __restrict__ brv,
    const void* __restrict__ WxHv, const void* __restrict__ WrHv,
    const void* __restrict__ bHv, const void* __restrict__ Whyv,
    const void* __restrict__ byv, void* __restrict__ outv,
    float* xbuf) {
  const T* Whz0 = (const T*)Whz0v; const T* bz0 = (const T*)bz0v;
  const T* Whr0 = (const T*)Whr0v; const T* br0 = (const T*)br0v;
  const T* WrH0 = (const T*)WrH0v; const T* bH0 = (const T*)bH0v;
  const T* Wxz = (const T*)Wxzv;   const T* Whz = (const T*)Whzv;
  const T* bz = (const T*)bzv;     const T* Wxr = (const T*)Wxrv;
  const T* Whr = (const T*)Whrv;   const T* br = (const T*)brv;
  const T* WxH = (const T*)WxHv;   const T* WrH = (const T*)WrHv;
  const T* bH = (const T*)bHv;     const T* Why = (const T*)Whyv;
  const T* by = (const T*)byv;     T* out = (T*)outv;

  const int tid = threadIdx.x;
  const int gi = tid >> 3;   // cell = l*GQ + g
  const int j = tid & 7;
  const int l = gi >> 2;     // GQ=4
  const int g = gi & 3;
  const int b = blockIdx.x * GQ + g;

  for (int i = tid; i < 2 * NCELL * XG; i += TPBR) xbuf[i] = 0.f;  // h0=0, l==0 x

  const int D[8] = {0, 1, 2, 3, 7, 6, 5, 4};  // DPP butterfly source order

  // ---- weights: z,r packed as {Wz[k][j], Wr[k][j]}; H-gate scalar (DPP order)
  v2f wzrx[8], wzrh[8], wxh2[4], bzr;
  float wrhS[8], vbh;
  if (l == 0) {
#pragma unroll
    for (int k = 0; k < 8; ++k) {
      wzrh[k] = mk2(toF(Whz0[k * 8 + j]), toF(Whr0[k * 8 + j]));
      wzrx[k] = mk2(0.f, 0.f);
    }
#pragma unroll
    for (int i = 0; i < 8; ++i) wrhS[i] = toF(WrH0[(j ^ D[i]) * 8 + j]);
#pragma unroll
    for (int q = 0; q < 4; ++q) wxh2[q] = mk2(0.f, 0.f);
    bzr = mk2(toF(bz0[j]), toF(br0[j]));
    vbh = toF(bH0[j]);
  } else {
    const int base = (l - 1) * 64;
#pragma unroll
    for (int k = 0; k < 8; ++k) {
      wzrx[k] = mk2(toF(Wxz[base + k * 8 + j]), toF(Wxr[base + k * 8 + j]));
      wzrh[k] = mk2(toF(Whz[base + k * 8 + j]), toF(Whr[base + k * 8 + j]));
    }
#pragma unroll
    for (int i = 0; i < 8; ++i) wrhS[i] = toF(WrH[base + (j ^ D[i]) * 8 + j]);
#pragma unroll
    for (int q = 0; q < 4; ++q)
      wxh2[q] = mk2(toF(WxH[base + (2 * q) * 8 + j]), toF(WxH[base + (2 * q + 1) * 8 + j]));
    bzr = mk2(toF(bz[(l - 1) * 8 + j]), toF(br[(l - 1) * 8 + j]));
    vbh = toF(bH[(l - 1) * 8 + j]);
  }
#pragma unroll
  for (int k = 0; k < 8; ++k) { PIN(wzrx[k]); PIN(wzrh[k]); PIN(wrhS[k]); }
#pragma unroll
  for (int q = 0; q < 4; ++q) { PIN(wxh2[q]); }
  PIN(bzr); PIN(vbh);

  // layer-0 precomputed x-projections for the 4 timesteps of this superstep
  const PT* ppr = pre + (size_t)b * (S_ * 24);
  v2f czr0 = mk2(0.f, 0.f), czr1 = czr0, czr2 = czr0, czr3 = czr0;
  float ch0 = 0.f, ch1 = 0.f, ch2 = 0.f, ch3 = 0.f;
  if (l == 0) {
    czr0 = loadC2(ppr + 0 * 24 + 2 * j);  ch0 = toF(ppr[0 * 24 + 16 + j]);
    czr1 = loadC2(ppr + 1 * 24 + 2 * j);  ch1 = toF(ppr[1 * 24 + 16 + j]);
    czr2 = loadC2(ppr + 2 * 24 + 2 * j);  ch2 = toF(ppr[2 * 24 + 16 + j]);
    czr3 = loadC2(ppr + 3 * 24 + 2 * j);  ch3 = toF(ppr[3 * 24 + 16 + j]);
  }

  const int gp = (gi >= GQ) ? (gi - GQ) * XG : 0;
  const float* xpe = xbuf + NCELL * XG + gp;  // consumer read when s even
  const float* xpo = xbuf + gp;               // consumer read when s odd
  float* xce = xbuf + gi * XG;                // own write when s even
  float* xco = xbuf + NCELL * XG + gi * XG;   // own write when s odd

  float hown = 0.f;

  __syncthreads();

  for (int s = 0; s < NSUPER; ++s) {
    const unsigned rel = (unsigned)(s - l);
    if (rel < (unsigned)(S_ / TS)) {
      const float* xp = (s & 1) ? xpo : xpe;
      float* xc = (s & 1) ? xco : xce;
      const float* xprev = (s & 1) ? xce : xco;  // own region of previous parity

      const v4f xa0 = ((const v4f*)xp)[0];
      const v4f xb0 = ((const v4f*)xp)[1];
      const v4f xa1 = ((const v4f*)xp)[2];
      const v4f xb1 = ((const v4f*)xp)[3];
      v4f xa2, xb2, xa3, xb3;
      v2f ax1, ax2c, ax3c;
      float axh1, axh2, axh3;
      float hn0, hn1, hn2, hn3;

      v2f nzr0 = mk2(0.f, 0.f), nzr1 = nzr0, nzr2 = nzr0, nzr3 = nzr0;
      float nh0 = 0.f, nh1 = 0.f, nh2 = 0.f, nh3 = 0.f;
      const bool pf = (l == 0) && (rel + 1u < (unsigned)(S_ / TS));

      // ---- T0 (h from own previous-parity slot 3; fills hide the h-read)
      {
        const v4f h01 = ((const v4f*)(xprev + 24))[0];
        const v4f h23 = ((const v4f*)(xprev + 24))[1];
        v2f ax0 = czr0; CHAIN8(ax0, xa0, xb0, wzrx);
        v2f ah0v = mk2(ch0, vbh); CHAIN4P(ah0v, xa0, xb0, wxh2);
        const float axh0 = ah0v.x + ah0v.y;
        ax1 = czr1; CHAIN8(ax1, xa1, xb1, wzrx);
        v2f ah1v = mk2(ch1, vbh); CHAIN4P(ah1v, xa1, xb1, wxh2);
        axh1 = ah1v.x + ah1v.y;
        xa2 = ((const v4f*)xp)[4];
        xb2 = ((const v4f*)xp)[5];
        TSTEP(hown, ax0, axh0, h01, h23, 0, hn0)
      }
      // ---- T1 (h from slot 0; T2 chains fill the h window)
      {
        const v4f h01 = ((const v4f*)xc)[0];
        const v4f h23 = ((const v4f*)xc)[1];
        xa3 = ((const v4f*)xp)[6];
        xb3 = ((const v4f*)xp)[7];
        ax2c = czr2; CHAIN8(ax2c, xa2, xb2, wzrx);
        v2f ah2v = mk2(ch2, vbh); CHAIN4P(ah2v, xa2, xb2, wxh2);
        axh2 = ah2v.x + ah2v.y;
        TSTEP(hn0, ax1, axh1, h01, h23, 1, hn1)
      }
      // ---- T2 (h from slot 1; T3 chains + l==0 prefetch fill the window)
      {
        const v4f h01 = ((const v4f*)(xc + 8))[0];
        const v4f h23 = ((const v4f*)(xc + 8))[1];
        ax3c = czr3; CHAIN8(ax3c, xa3, xb3, wzrx);
        v2f ah3v = mk2(ch3, vbh); CHAIN4P(ah3v, xa3, xb3, wxh2);
        axh3 = ah3v.x + ah3v.y;
        if (pf) {
          const PT* pn = ppr + (TS * rel + 4) * 24;
          nzr0 = loadC2(pn + 0 * 24 + 2 * j);  nh0 = toF(pn[0 * 24 + 16 + j]);
          nzr1 = loadC2(pn + 1 * 24 + 2 * j);  nh1 = toF(pn[1 * 24 + 16 + j]);
          nzr2 = loadC2(pn + 2 * 24 + 2 * j);  nh2 = toF(pn[2 * 24 + 16 + j]);
          nzr3 = loadC2(pn + 3 * 24 + 2 * j);  nh3 = toF(pn[3 * 24 + 16 + j]);
        }
        TSTEP(hn1, ax2c, axh2, h01, h23, 2, hn2)
      }
      // ---- T3 (h from slot 2)
      {
        const v4f h01 = ((const v4f*)(xc + 16))[0];
        const v4f h23 = ((const v4f*)(xc + 16))[1];
        TSTEP(hn2, ax3c, axh3, h01, h23, 3, hn3)
      }

      hown = hn3;
      czr0 = nzr0; ch0 = nh0; czr1 = nzr1; ch1 = nh1;
      czr2 = nzr2; ch2 = nh2; czr3 = nzr3; ch3 = nh3;
    }
    __syncthreads();
  }

  // ---- epilogue ----
  stP(out + B_ + (l * B_ + b) * H_ + j, hown);
  if (l == L_ - 1 && j == 0) {
    // final superstep for layer L-1 is s=151 (odd) -> writes went to xco slot 3
    const float* hf = xbuf + NCELL * XG + gi * XG + 24;
    float ssum = toF(by[0]);
#pragma unroll
    for (int k = 0; k < 8; ++k) ssum = fmaf(hf[k], toF(Why[k]), ssum);
    stP(out + b, ssum);
  }
}

template <typename PT>
__global__ __launch_bounds__(TPBR, 4) void gru_rec(
    const void* __restrict__ emb, const PT* __restrict__ pre,
    const void* __restrict__ Whz0, const void* __restrict__ bz0,
    const void* __restrict__ Whr0, const void* __restrict__ br0,
    const void* __restrict__ WrH0, const void* __restrict__ bH0,
    const void* __restrict__ Wxz, const void* __restrict__ Whz,
    const void* __restrict__ bz, const void* __restrict__ Wxr,
    const void* __restrict__ Whr, const void* __restrict__ br,
    const void* __restrict__ WxH, const void* __restrict__ WrH,
    const void* __restrict__ bH, const void* __restrict__ Why,
    const void* __restrict__ by, void* __restrict__ out) {
  __shared__ __align__(16) float xbuf[2 * NCELL * XG];
  __shared__ float fl;
  detect64((const unsigned short*)emb, threadIdx.x, &fl);
  __syncthreads();
  if (fl != 0.f)
    rec_body<__hip_bfloat16, PT>(pre, Whz0, bz0, Whr0, br0, WrH0, bH0, Wxz, Whz,
                                 bz, Wxr, Whr, br, WxH, WrH, bH, Why, by, out,
                                 xbuf);
  else
    rec_body<float, PT>(pre, Whz0, bz0, Whr0, br0, WrH0, bH0, Wxz, Whz, bz, Wxr,
                        Whr, br, WxH, WrH, bH, Why, by, out, xbuf);
}

// ---------------------------------------------------------------------------
template <typename PT>
static void launch_all(void* const* d_in, PT* pre, void* d_out, hipStream_t stream) {
  gru_pre<PT><<<B_ * S_ / 256, 256, 0, stream>>>(
      (const int*)d_in[0], d_in[1], d_in[2], d_in[5], d_in[8], pre);
  gru_rec<PT><<<B_ / GQ, TPBR, 0, stream>>>(
      d_in[1], pre, d_in[3], d_in[4], d_in[6], d_in[7], d_in[9], d_in[10],
      d_in[11], d_in[12], d_in[13], d_in[14], d_in[15], d_in[16], d_in[17],
      d_in[18], d_in[19], d_in[20], d_in[21], d_out);
}

extern "C" void kernel_launch(void* const* d_in, const int* in_sizes, int n_in,
                              void* d_out, int out_size, void* d_ws, size_t ws_size,
                              hipStream_t stream) {
  const size_t needF = (size_t)B_ * S_ * 24 * sizeof(float);
  if (ws_size >= needF)
    launch_all<float>(d_in, (float*)d_ws, d_out, stream);
  else
    launch_all<__hip_bfloat16>(d_in, (__hip_bfloat16*)d_ws, d_out, stream);
}

// Round 12
// 390.737 us; speedup vs baseline: 1.0659x; 1.0659x over previous
//
#include <hip/hip_runtime.h>
#include <hip/hip_bf16.h>
#include <stdint.h>

#define L_ 25
#define E_ 64
#define H_ 8
#define B_ 1000
#define S_ 512
#define GQ 4                       // batch elements per block
#define NCELL (L_ * GQ)            // 100 cells per block
#define TPBR (NCELL * 8)           // 800 threads, thread = (cell, j)
#define TS 4                       // timesteps per superstep
#define NSUPER (S_ / TS + L_ - 1)  // 152 supersteps
#define HS 12                      // per-cell stride hrsh: 48B, banks disjoint
#define XG 36                      // per-cell stride xbuf: 144B (16B-aligned)
#define TOK 4                      // tokens per thread in gru_pre (W-read amortization)

typedef float v2f __attribute__((ext_vector_type(2)));
typedef float v4f __attribute__((ext_vector_type(4)));

#define PIN(x) asm volatile("" : "+v"(x))
#define LGKM0() asm volatile("s_waitcnt lgkmcnt(0)" ::: "memory")

// v_pk_fma_f32: {a.x*b.x+c.x, a.y*b.y+c.y}
__device__ __forceinline__ v2f pkfma(v2f a, v2f b, v2f c) {
  v2f d;
  asm("v_pk_fma_f32 %0, %1, %2, %3" : "=v"(d) : "v"(a), "v"(b), "v"(c));
  return d;
}
// op_sel broadcast of a.x: {a.x*b.x+c.x, a.x*b.y+c.y}
__device__ __forceinline__ v2f pkfma_l(v2f a, v2f b, v2f c) {
  v2f d;
  asm("v_pk_fma_f32 %0, %1, %2, %3 op_sel:[0,0,0] op_sel_hi:[0,1,1]"
      : "=v"(d) : "v"(a), "v"(b), "v"(c));
  return d;
}
// op_sel broadcast of a.y: {a.y*b.x+c.x, a.y*b.y+c.y}
__device__ __forceinline__ v2f pkfma_h(v2f a, v2f b, v2f c) {
  v2f d;
  asm("v_pk_fma_f32 %0, %1, %2, %3 op_sel:[1,0,0] op_sel_hi:[1,1,1]"
      : "=v"(d) : "v"(a), "v"(b), "v"(c));
  return d;
}
__device__ __forceinline__ v2f pkadd(v2f a, v2f b) {
  v2f d;
  asm("v_pk_add_f32 %0, %1, %2" : "=v"(d) : "v"(a), "v"(b));
  return d;
}
__device__ __forceinline__ v2f vlo(v4f v) { return __builtin_shufflevector(v, v, 0, 1); }
__device__ __forceinline__ v2f vhi(v4f v) { return __builtin_shufflevector(v, v, 2, 3); }
__device__ __forceinline__ v2f mk2(float a, float b) { v2f r; r.x = a; r.y = b; return r; }

// zr chain over 8 k's: acc.{x=z,y=r} += sum_k m[k] * {Wz,Wr}[k]
#define CHAIN8(acc, ma, mb, w)            \
  acc = pkfma_l(vlo(ma), w[0], acc);      \
  acc = pkfma_h(vlo(ma), w[1], acc);      \
  acc = pkfma_l(vhi(ma), w[2], acc);      \
  acc = pkfma_h(vhi(ma), w[3], acc);      \
  acc = pkfma_l(vlo(mb), w[4], acc);      \
  acc = pkfma_h(vlo(mb), w[5], acc);      \
  acc = pkfma_l(vhi(mb), w[6], acc);      \
  acc = pkfma_h(vhi(mb), w[7], acc);

// element-wise paired chain: acc += {m[2q]*w[q].x, m[2q+1]*w[q].y}
#define CHAIN4P(acc, ma, mb, w)           \
  acc = pkfma(vlo(ma), w[0], acc);        \
  acc = pkfma(vhi(ma), w[1], acc);        \
  acc = pkfma(vlo(mb), w[2], acc);        \
  acc = pkfma(vhi(mb), w[3], acc);

__device__ __forceinline__ float ulo(uint32_t u) { return __uint_as_float(u << 16); }
__device__ __forceinline__ float uhi(uint32_t u) { return __uint_as_float(u & 0xffff0000u); }

__device__ __forceinline__ float toF(float v) { return v; }
__device__ __forceinline__ float toF(__hip_bfloat16 v) { return __bfloat162float(v); }
__device__ __forceinline__ void stP(float* p, float v) { *p = v; }
__device__ __forceinline__ void stP(__hip_bfloat16* p, float v) { *p = __float2bfloat16(v); }

__device__ __forceinline__ v2f loadC2(const float* p) { return *(const v2f*)p; }
__device__ __forceinline__ v2f loadC2(const __hip_bfloat16* p) {
  const uint32_t u = *(const uint32_t*)p;
  return mk2(ulo(u), uhi(u));
}

__device__ __forceinline__ void load8f(const __hip_bfloat16* p, float* o) {
  const uint4 v = *(const uint4*)p;
  o[0] = ulo(v.x); o[1] = uhi(v.x); o[2] = ulo(v.y); o[3] = uhi(v.y);
  o[4] = ulo(v.z); o[5] = uhi(v.z); o[6] = ulo(v.w); o[7] = uhi(v.w);
}
__device__ __forceinline__ void load8f(const float* p, float* o) {
  const float4 a = ((const float4*)p)[0];
  const float4 b = ((const float4*)p)[1];
  o[0] = a.x; o[1] = a.y; o[2] = a.z; o[3] = a.w;
  o[4] = b.x; o[5] = b.y; o[6] = b.z; o[7] = b.w;
}

__device__ __forceinline__ void st4(float* p, float a, float b, float c, float d) {
  float4 v; v.x = a; v.y = b; v.z = c; v.w = d;
  *(float4*)p = v;
}
__device__ __forceinline__ void st4(__hip_bfloat16* p, float a, float b, float c, float d) {
  __hip_bfloat16 t[4] = {__float2bfloat16(a), __float2bfloat16(b),
                         __float2bfloat16(c), __float2bfloat16(d)};
  *(ushort4*)p = *(ushort4*)t;
}

__device__ __forceinline__ float sigmo(float x) {
  return __builtin_amdgcn_rcpf(1.f + __expf(-x));
}

// Per-block dtype probe: max |bf16| of first 256 shorts of emb.
__device__ __forceinline__ void detect64(const unsigned short* __restrict__ u,
                                         int tid, float* fl) {
  if (tid < 64) {
    float m = 0.f;
#pragma unroll
    for (int k = 0; k < 4; ++k) {
      const uint32_t q = u[tid * 4 + k];
      float v = fabsf(__uint_as_float(q << 16));
      if (!(v < 1e30f)) v = 1e30f;
      m = fmaxf(m, v);
    }
#pragma unroll
    for (int off = 32; off; off >>= 1) m = fmaxf(m, __shfl_down(m, off, 64));
    if (tid == 0) *fl = (m > 2.0f) ? 0.f : 1.f;
  }
}

// ---------------------------------------------------------------------------
// Kernel 1: layer-0 x-projections, TOK=4 tokens/thread.
// Each WL (weight) LDS read is amortized over 4 tokens -> LDS issue /4
// (the old 1-token version re-read all 1536 weight floats per token and was
// LDS-throughput bound at ~90 us; roofline is ~30 us).
// Thread owns tokens chunk + lane + 64p, so transpose pass p covers 64
// CONSECUTIVE tokens -> stores stay fully coalesced.
// pre token layout (24 floats): [2j]={z_j}, [2j+1]={r_j}, [16+j]={h_j}.
// ---------------------------------------------------------------------------
template <typename T, typename PT>
__device__ __forceinline__ void pre_body(
    const int* __restrict__ x, const void* __restrict__ embv,
    const void* __restrict__ Wzv, const void* __restrict__ Wrv,
    const void* __restrict__ Whv, PT* __restrict__ pre,
    float* WL, float* TBb) {
  const T* emb = (const T*)embv;
  const T* Wz = (const T*)Wzv;
  const T* Wr = (const T*)Wrv;
  const T* Wh = (const T*)Whv;
  const int tid = threadIdx.x;

  for (int idx = tid; idx < 64 * 24; idx += 256) {
    const int k = idx / 24, c = idx - k * 24;
    float w;
    if (c < 16) w = toF(((c & 1) ? Wr : Wz)[k * 8 + (c >> 1)]);
    else        w = toF(Wh[k * 8 + (c - 16)]);
    WL[idx] = w;
  }
  __syncthreads();

  const int wid = tid >> 6, lane = tid & 63;
  const int chunk = blockIdx.x * (256 * TOK) + wid * (64 * TOK);  // wave's tokens
  const T* erow[TOK];
#pragma unroll
  for (int p = 0; p < TOK; ++p) {
    const int t = x[chunk + p * 64 + lane];
    erow[p] = emb + (size_t)t * E_;
  }

  v2f acc[TOK][12];
#pragma unroll
  for (int p = 0; p < TOK; ++p)
#pragma unroll
    for (int q = 0; q < 12; ++q) acc[p][q] = mk2(0.f, 0.f);

  for (int kb = 0; kb < 8; ++kb) {
    float e[TOK][8];
#pragma unroll
    for (int p = 0; p < TOK; ++p) load8f(erow[p] + kb * 8, e[p]);
#pragma unroll
    for (int k8 = 0; k8 < 8; ++k8) {
      const v4f* wr = (const v4f*)(WL + (kb * 8 + k8) * 24);
#pragma unroll
      for (int q = 0; q < 6; ++q) {
        const v4f w4 = wr[q];           // one LDS read feeds 4 tokens
        const v2f wl = vlo(w4), wh = vhi(w4);
#pragma unroll
        for (int p = 0; p < TOK; ++p) {
          const v2f ee = mk2(e[p][k8], e[p][k8]);
          acc[p][2 * q]     = pkfma(ee, wl, acc[p][2 * q]);
          acc[p][2 * q + 1] = pkfma(ee, wh, acc[p][2 * q + 1]);
        }
      }
    }
  }

  // per-wave transpose [24][65] (conflict-free), one pass per token set;
  // pass p covers tokens chunk+64p .. +63 (consecutive -> coalesced store)
  float* tb = TBb + wid * (24 * 65);
#pragma unroll
  for (int p = 0; p < TOK; ++p) {
#pragma unroll
    for (int q = 0; q < 12; ++q) {
      tb[(2 * q) * 65 + lane] = acc[p][q].x;
      tb[(2 * q + 1) * 65 + lane] = acc[p][q].y;
    }
    LGKM0();
    __builtin_amdgcn_wave_barrier();

    PT* ob = pre + (size_t)(chunk + p * 64) * 24;
#pragma unroll
    for (int it = 0; it < 6; ++it) {
      const int F0 = it * 256 + lane * 4;
      float o[4];
#pragma unroll
      for (int e2 = 0; e2 < 4; ++e2) {
        const int F = F0 + e2;
        const int tk = F / 24;
        const int c = F - tk * 24;
        o[e2] = tb[c * 65 + tk];
      }
      st4(ob + F0, o[0], o[1], o[2], o[3]);
    }
    LGKM0();                       // ds reads of this pass retired
    __builtin_amdgcn_wave_barrier();
  }
}

template <typename PT>
__global__ __launch_bounds__(256, 2) void gru_pre(
    const int* __restrict__ x, const void* __restrict__ emb,
    const void* __restrict__ Wz, const void* __restrict__ Wr,
    const void* __restrict__ Wh, PT* __restrict__ pre) {
  __shared__ __align__(16) float WL[64 * 24];
  __shared__ __align__(16) float TB[4][24 * 65];
  __shared__ float fl;
  detect64((const unsigned short*)emb, threadIdx.x, &fl);
  __syncthreads();
  if (fl != 0.f) pre_body<__hip_bfloat16, PT>(x, emb, Wz, Wr, Wh, pre, WL, &TB[0][0]);
  else           pre_body<float, PT>(x, emb, Wz, Wr, Wh, pre, WL, &TB[0][0]);
}

// ---------------------------------------------------------------------------
// Kernel 2: pipelined recurrence — R8 verbatim (best measured: 294.1 us).
// TS=4, GQ=4, global __syncthreads; h-exchange unified into xbuf (the xc slot
// writes double as the intra-cell h exchange); independent x-chains and tile
// loads placed inside each timestep's ds round-trip windows.
// ---------------------------------------------------------------------------
template <typename T, typename PT>
__device__ __forceinline__ void rec_body(
    const PT* __restrict__ pre,
    const void* __restrict__ Whz0v, const void* __restrict__ bz0v,
    const void* __restrict__ Whr0v, const void* __restrict__ br0v,
    const void* __restrict__ WrH0v, const void* __restrict__ bH0v,
    const void* __restrict__ Wxzv, const void* __restrict__ Whzv,
    const void* __restrict__ bzv, const void* __restrict__ Wxrv,
    const void* __restrict__ Whrv, const void* __restrict__ brv,
    const void* __restrict__ WxHv, const void* __restrict__ WrHv,
    const void* __restrict__ bHv, const void* __restrict__ Whyv,
    const void* __restrict__ byv, void* __restrict__ outv,
    float* hrsh, float* xbuf) {
  const T* Whz0 = (const T*)Whz0v; const T* bz0 = (const T*)bz0v;
  const T* Whr0 = (const T*)Whr0v; const T* br0 = (const T*)br0v;
  const T* WrH0 = (const T*)WrH0v; const T* bH0 = (const T*)bH0v;
  const T* Wxz = (const T*)Wxzv;   const T* Whz = (const T*)Whzv;
  const T* bz = (const T*)bzv;     const T* Wxr = (const T*)Wxrv;
  const T* Whr = (const T*)Whrv;   const T* br = (const T*)brv;
  const T* WxH = (const T*)WxHv;   const T* WrH = (const T*)WrHv;
  const T* bH = (const T*)bHv;     const T* Why = (const T*)Whyv;
  const T* by = (const T*)byv;     T* out = (T*)outv;

  const int tid = threadIdx.x;
  const int gi = tid >> 3;   // cell = l*GQ + g
  const int j = tid & 7;
  const int l = gi >> 2;     // GQ=4
  const int g = gi & 3;
  const int b = blockIdx.x * GQ + g;

  for (int i = tid; i < 2 * NCELL * XG; i += TPBR) xbuf[i] = 0.f;  // h0=0, l==0 x

  // ---- weights: z,r packed as {Wz[k][j], Wr[k][j]}; H-gate k-paired ----
  v2f wzrx[8], wzrh[8], wxh2[4], wrh2[4], bzr;
  float vbh;
  if (l == 0) {
#pragma unroll
    for (int k = 0; k < 8; ++k) {
      wzrh[k] = mk2(toF(Whz0[k * 8 + j]), toF(Whr0[k * 8 + j]));
      wzrx[k] = mk2(0.f, 0.f);
    }
#pragma unroll
    for (int q = 0; q < 4; ++q) {
      wrh2[q] = mk2(toF(WrH0[(2 * q) * 8 + j]), toF(WrH0[(2 * q + 1) * 8 + j]));
      wxh2[q] = mk2(0.f, 0.f);
    }
    bzr = mk2(toF(bz0[j]), toF(br0[j]));
    vbh = toF(bH0[j]);
  } else {
    const int base = (l - 1) * 64;
#pragma unroll
    for (int k = 0; k < 8; ++k) {
      wzrx[k] = mk2(toF(Wxz[base + k * 8 + j]), toF(Wxr[base + k * 8 + j]));
      wzrh[k] = mk2(toF(Whz[base + k * 8 + j]), toF(Whr[base + k * 8 + j]));
    }
#pragma unroll
    for (int q = 0; q < 4; ++q) {
      wxh2[q] = mk2(toF(WxH[base + (2 * q) * 8 + j]), toF(WxH[base + (2 * q + 1) * 8 + j]));
      wrh2[q] = mk2(toF(WrH[base + (2 * q) * 8 + j]), toF(WrH[base + (2 * q + 1) * 8 + j]));
    }
    bzr = mk2(toF(bz[(l - 1) * 8 + j]), toF(br[(l - 1) * 8 + j]));
    vbh = toF(bH[(l - 1) * 8 + j]);
  }
#pragma unroll
  for (int k = 0; k < 8; ++k) { PIN(wzrx[k]); PIN(wzrh[k]); }
#pragma unroll
  for (int q = 0; q < 4; ++q) { PIN(wxh2[q]); PIN(wrh2[q]); }
  PIN(bzr); PIN(vbh);

  // layer-0 precomputed x-projections for the 4 timesteps of this superstep
  const PT* ppr = pre + (size_t)b * (S_ * 24);
  v2f czr0 = mk2(0.f, 0.f), czr1 = czr0, czr2 = czr0, czr3 = czr0;
  float ch0 = 0.f, ch1 = 0.f, ch2 = 0.f, ch3 = 0.f;
  if (l == 0) {
    czr0 = loadC2(ppr + 0 * 24 + 2 * j);  ch0 = toF(ppr[0 * 24 + 16 + j]);
    czr1 = loadC2(ppr + 1 * 24 + 2 * j);  ch1 = toF(ppr[1 * 24 + 16 + j]);
    czr2 = loadC2(ppr + 2 * 24 + 2 * j);  ch2 = toF(ppr[2 * 24 + 16 + j]);
    czr3 = loadC2(ppr + 3 * 24 + 2 * j);  ch3 = toF(ppr[3 * 24 + 16 + j]);
  }

  float* hrg = hrsh + gi * HS;
  float* hrgj = hrg + j;
  const int gp = (gi >= GQ) ? (gi - GQ) * XG : 0;
  const float* xpe = xbuf + NCELL * XG + gp;  // consumer read when s even
  const float* xpo = xbuf + gp;               // consumer read when s odd
  float* xce = xbuf + gi * XG;                // own write when s even
  float* xco = xbuf + NCELL * XG + gi * XG;   // own write when s odd

  float hown = 0.f;

  __syncthreads();

  for (int s = 0; s < NSUPER; ++s) {
    const unsigned rel = (unsigned)(s - l);
    if (rel < (unsigned)(S_ / TS)) {
      const float* xp = (s & 1) ? xpo : xpe;
      float* xc = (s & 1) ? xco : xce;
      const float* xprev = (s & 1) ? xce : xco;  // own region of previous parity

      const v4f xa0 = ((const v4f*)xp)[0];
      const v4f xb0 = ((const v4f*)xp)[1];
      const v4f xa1 = ((const v4f*)xp)[2];
      const v4f xb1 = ((const v4f*)xp)[3];
      v4f xa2, xb2, xa3, xb3;
      v2f ax1, ah1v, ax2c, ah2v, ax3c, ah3v;
      float hn0, hn1, hn2, hn3;

      v2f nzr0 = mk2(0.f, 0.f), nzr1 = nzr0, nzr2 = nzr0, nzr3 = nzr0;
      float nh0 = 0.f, nh1 = 0.f, nh2 = 0.f, nh3 = 0.f;
      const bool pf = (l == 0) && (rel + 1u < (unsigned)(S_ / TS));

      // =================== T0 ===================
      {
        const v4f h01 = ((const v4f*)(xprev + 24))[0];  // own h of last superstep
        const v4f h23 = ((const v4f*)(xprev + 24))[1];
        // fill h-read latency: T0 + T1 x-chains (independent)
        v2f ax0 = czr0; CHAIN8(ax0, xa0, xb0, wzrx);
        v2f ah0v = mk2(ch0, vbh); CHAIN4P(ah0v, xa0, xb0, wxh2);
        ax1 = czr1; CHAIN8(ax1, xa1, xb1, wzrx);
        ah1v = mk2(ch1, vbh); CHAIN4P(ah1v, xa1, xb1, wxh2);
        v2f azrh = bzr; CHAIN8(azrh, h01, h23, wzrh);
        const v2f azr = pkadd(azrh, ax0);
        const float r_ = sigmo(azr.y);
        *hrgj = hown * r_;
        __builtin_amdgcn_wave_barrier();
        const v4f r01 = ((const v4f*)hrg)[0];
        const v4f r23 = ((const v4f*)hrg)[1];
        xa2 = ((const v4f*)xp)[4];  // issue T2 tile loads into the hr window
        xb2 = ((const v4f*)xp)[5];
        CHAIN4P(ah0v, r01, r23, wrh2);
        const float ah_ = ah0v.x + ah0v.y;
        const float ez_ = __expf(fminf(-azr.x, 30.f));
        const float eh_ = __expf(fminf(-2.f * ah_, 30.f));
        const float t_ = hown * ez_;
        const float nu_ = fmaf(eh_, t_ - 1.f, t_ + 1.f);
        const float de_ = (1.f + ez_) * (1.f + eh_);
        hn0 = nu_ * __builtin_amdgcn_rcpf(de_);
        xc[j] = hn0;
        __builtin_amdgcn_wave_barrier();
      }
      // =================== T1 ===================
      {
        const v4f h01 = ((const v4f*)xc)[0];   // slot 0 (= h after T0)
        const v4f h23 = ((const v4f*)xc)[1];
        xa3 = ((const v4f*)xp)[6];             // issue T3 tile loads
        xb3 = ((const v4f*)xp)[7];
        // fill h-read latency: T2 x-chains
        ax2c = czr2; CHAIN8(ax2c, xa2, xb2, wzrx);
        ah2v = mk2(ch2, vbh); CHAIN4P(ah2v, xa2, xb2, wxh2);
        v2f azrh = bzr; CHAIN8(azrh, h01, h23, wzrh);
        const v2f azr = pkadd(azrh, ax1);
        const float r_ = sigmo(azr.y);
        *hrgj = hn0 * r_;
        __builtin_amdgcn_wave_barrier();
        const v4f r01 = ((const v4f*)hrg)[0];
        const v4f r23 = ((const v4f*)hrg)[1];
        // fill hr-read latency: T3 x-chains
        ax3c = czr3; CHAIN8(ax3c, xa3, xb3, wzrx);
        ah3v = mk2(ch3, vbh); CHAIN4P(ah3v, xa3, xb3, wxh2);
        CHAIN4P(ah1v, r01, r23, wrh2);
        const float ah_ = ah1v.x + ah1v.y;
        const float ez_ = __expf(fminf(-azr.x, 30.f));
        const float eh_ = __expf(fminf(-2.f * ah_, 30.f));
        const float t_ = hn0 * ez_;
        const float nu_ = fmaf(eh_, t_ - 1.f, t_ + 1.f);
        const float de_ = (1.f + ez_) * (1.f + eh_);
        hn1 = nu_ * __builtin_amdgcn_rcpf(de_);
        xc[8 + j] = hn1;
        __builtin_amdgcn_wave_barrier();
      }
      // =================== T2 ===================
      {
        const v4f h01 = ((const v4f*)(xc + 8))[0];  // slot 1
        const v4f h23 = ((const v4f*)(xc + 8))[1];
        // fill h-read latency: l==0 global prefetch (vmcnt, overlaps freely)
        if (pf) {
          const PT* pn = ppr + (TS * rel + 4) * 24;
          nzr0 = loadC2(pn + 0 * 24 + 2 * j);  nh0 = toF(pn[0 * 24 + 16 + j]);
          nzr1 = loadC2(pn + 1 * 24 + 2 * j);  nh1 = toF(pn[1 * 24 + 16 + j]);
          nzr2 = loadC2(pn + 2 * 24 + 2 * j);  nh2 = toF(pn[2 * 24 + 16 + j]);
          nzr3 = loadC2(pn + 3 * 24 + 2 * j);  nh3 = toF(pn[3 * 24 + 16 + j]);
        }
        v2f azrh = bzr; CHAIN8(azrh, h01, h23, wzrh);
        const v2f azr = pkadd(azrh, ax2c);
        const float r_ = sigmo(azr.y);
        *hrgj = hn1 * r_;
        __builtin_amdgcn_wave_barrier();
        const v4f r01 = ((const v4f*)hrg)[0];
        const v4f r23 = ((const v4f*)hrg)[1];
        CHAIN4P(ah2v, r01, r23, wrh2);
        const float ah_ = ah2v.x + ah2v.y;
        const float ez_ = __expf(fminf(-azr.x, 30.f));
        const float eh_ = __expf(fminf(-2.f * ah_, 30.f));
        const float t_ = hn1 * ez_;
        const float nu_ = fmaf(eh_, t_ - 1.f, t_ + 1.f);
        const float de_ = (1.f + ez_) * (1.f + eh_);
        hn2 = nu_ * __builtin_amdgcn_rcpf(de_);
        xc[16 + j] = hn2;
        __builtin_amdgcn_wave_barrier();
      }
      // =================== T3 ===================
      {
        const v4f h01 = ((const v4f*)(xc + 16))[0];  // slot 2
        const v4f h23 = ((const v4f*)(xc + 16))[1];
        v2f azrh = bzr; CHAIN8(azrh, h01, h23, wzrh);
        const v2f azr = pkadd(azrh, ax3c);
        const float r_ = sigmo(azr.y);
        *hrgj = hn2 * r_;
        __builtin_amdgcn_wave_barrier();
        const v4f r01 = ((const v4f*)hrg)[0];
        const v4f r23 = ((const v4f*)hrg)[1];
        CHAIN4P(ah3v, r01, r23, wrh2);
        const float ah_ = ah3v.x + ah3v.y;
        const float ez_ = __expf(fminf(-azr.x, 30.f));
        const float eh_ = __expf(fminf(-2.f * ah_, 30.f));
        const float t_ = hn2 * ez_;
        const float nu_ = fmaf(eh_, t_ - 1.f, t_ + 1.f);
        const float de_ = (1.f + ez_) * (1.f + eh_);
        hn3 = nu_ * __builtin_amdgcn_rcpf(de_);
        xc[24 + j] = hn3;
        __builtin_amdgcn_wave_barrier();
      }

      hown = hn3;
      czr0 = nzr0; ch0 = nh0; czr1 = nzr1; ch1 = nh1;
      czr2 = nzr2; ch2 = nh2; czr3 = nzr3; ch3 = nh3;
    }
    __syncthreads();
  }

  // ---- epilogue ----
  stP(out + B_ + (l * B_ + b) * H_ + j, hown);
  if (l == L_ - 1 && j == 0) {
    // final superstep for layer L-1 is s=151 (odd) -> writes went to xco slot 3
    const float* hf = xbuf + NCELL * XG + gi * XG + 24;
    float ssum = toF(by[0]);
#pragma unroll
    for (int k = 0; k < 8; ++k) ssum = fmaf(hf[k], toF(Why[k]), ssum);
    stP(out + b, ssum);
  }
}

template <typename PT>
__global__ __launch_bounds__(TPBR, 4) void gru_rec(
    const void* __restrict__ emb, const PT* __restrict__ pre,
    const void* __restrict__ Whz0, const void* __restrict__ bz0,
    const void* __restrict__ Whr0, const void* __restrict__ br0,
    const void* __restrict__ WrH0, const void* __restrict__ bH0,
    const void* __restrict__ Wxz, const void* __restrict__ Whz,
    const void* __restrict__ bz, const void* __restrict__ Wxr,
    const void* __restrict__ Whr, const void* __restrict__ br,
    const void* __restrict__ WxH, const void* __restrict__ WrH,
    const void* __restrict__ bH, const void* __restrict__ Why,
    const void* __restrict__ by, void* __restrict__ out) {
  __shared__ __align__(16) float hrsh[NCELL * HS];
  __shared__ __align__(16) float xbuf[2 * NCELL * XG];
  __shared__ float fl;
  detect64((const unsigned short*)emb, threadIdx.x, &fl);
  __syncthreads();
  if (fl != 0.f)
    rec_body<__hip_bfloat16, PT>(pre, Whz0, bz0, Whr0, br0, WrH0, bH0, Wxz, Whz,
                                 bz, Wxr, Whr, br, WxH, WrH, bH, Why, by, out,
                                 hrsh, xbuf);
  else
    rec_body<float, PT>(pre, Whz0, bz0, Whr0, br0, WrH0, bH0, Wxz, Whz, bz, Wxr,
                        Whr, br, WxH, WrH, bH, Why, by, out, hrsh, xbuf);
}

// ---------------------------------------------------------------------------
template <typename PT>
static void launch_all(void* const* d_in, PT* pre, void* d_out, hipStream_t stream) {
  gru_pre<PT><<<B_ * S_ / (256 * TOK), 256, 0, stream>>>(
      (const int*)d_in[0], d_in[1], d_in[2], d_in[5], d_in[8], pre);
  gru_rec<PT><<<B_ / GQ, TPBR, 0, stream>>>(
      d_in[1], pre, d_in[3], d_in[4], d_in[6], d_in[7], d_in[9], d_in[10],
      d_in[11], d_in[12], d_in[13], d_in[14], d_in[15], d_in[16], d_in[17],
      d_in[18], d_in[19], d_in[20], d_in[21], d_out);
}

extern "C" void kernel_launch(void* const* d_in, const int* in_sizes, int n_in,
                              void* d_out, int out_size, void* d_ws, size_t ws_size,
                              hipStream_t stream) {
  const size_t needF = (size_t)B_ * S_ * 24 * sizeof(float);
  if (ws_size >= needF)
    launch_all<float>(d_in, (float*)d_ws, d_out, stream);
  else
    launch_all<__hip_bfloat16>(d_in, (__hip_bfloat16*)d_ws, d_out, stream);
}